// Round 6
// baseline (166.051 us; speedup 1.0000x reference)
//
#include <hip/hip_runtime.h>

#define B_  4
#define C_  256
#define C8_ 32
#define N_  4096   // H*W

#define TJ 128     // j-tile per flash block
#define KI 64      // i per iteration
#define SPLITS 4   // i-range splits

typedef __attribute__((ext_vector_type(8)))  short bf16x8;   // MFMA A/B frag (8 bf16)
typedef __attribute__((ext_vector_type(16))) float f32x16;   // MFMA C/D frag

union FragAB { bf16x8 v; unsigned short u[8]; };

__device__ __forceinline__ unsigned short f2bf(float x) {
    unsigned u = __float_as_uint(x);
    unsigned r = u + 0x7FFFu + ((u >> 16) & 1u);   // RNE
    return (unsigned short)(r >> 16);
}
__device__ __forceinline__ unsigned pack2bf(float a, float b) {
    return (unsigned)f2bf(a) | ((unsigned)f2bf(b) << 16);
}
__device__ __forceinline__ float bf2f(unsigned short h) {
    return __uint_as_float(((unsigned)h) << 16);
}

// ---------------- prep: W concat -> bf16 [320][256] ----------------
__global__ __launch_bounds__(256) void prep_w_kernel(
    const float* __restrict__ Wq, const float* __restrict__ Wk,
    const float* __restrict__ Wv, unsigned short* __restrict__ Wbf)
{
    int idx = (blockIdx.x * 256 + threadIdx.x) * 4;   // grid 80 -> 81920 elems
    int row = idx >> 8;
    int col = idx & 255;
    const float* src; int r;
    if (row < 32)      { src = Wq; r = row;      }
    else if (row < 64) { src = Wk; r = row - 32; }
    else               { src = Wv; r = row - 64; }
    float4 v = *(const float4*)&src[r * 256 + col];
    uint2 o; o.x = pack2bf(v.x, v.y); o.y = pack2bf(v.z, v.w);
    *(uint2*)&Wbf[idx] = o;
}

// ---------------- prep: x [b][c][n] fp32 -> xT [b][n][c] bf16 ----------------
__global__ __launch_bounds__(256) void prep_x_kernel(
    const float* __restrict__ x, unsigned short* __restrict__ xT)
{
    __shared__ unsigned short T[64][66];
    int t  = threadIdx.x;
    int b  = blockIdx.z;
    int c0 = blockIdx.y * 64;
    int n0 = blockIdx.x * 64;
    const float* xb = x + (size_t)b * C_ * N_;
    int n_l = t & 63, c_l = t >> 6;
#pragma unroll
    for (int q = 0; q < 16; ++q) {
        int c = c_l * 16 + q;
        T[n_l][c] = f2bf(xb[(size_t)(c0 + c) * N_ + n0 + n_l]);
    }
    __syncthreads();
    unsigned short* xTb = xT + (size_t)b * N_ * C_;
    int c_l2 = t & 63, nb = t >> 6;
#pragma unroll
    for (int q = 0; q < 16; ++q) {
        int n = nb * 16 + q;
        xTb[(size_t)(n0 + n) * C_ + c0 + c_l2] = T[n][c_l2];
    }
}

// ---------------- MFMA projection ----------------
// f is written TRANSPOSED: fTg[b][n][32] so flash can 16B-load A-frags.
__global__ __launch_bounds__(256) void proj_mfma_kernel(
    const unsigned short* __restrict__ Wbf, const unsigned short* __restrict__ xT,
    unsigned short* __restrict__ fTg, unsigned short* __restrict__ g,
    unsigned short* __restrict__ hv)
{
    int t = threadIdx.x, w = t >> 6, lane = t & 63;
    int half = lane >> 5, l31 = lane & 31;
    int b  = blockIdx.y;
    int n0 = blockIdx.x * 32;

    const unsigned short* xb = xT + ((size_t)b * N_ + n0 + l31) * C_;
    int nm = (w < 2) ? 3 : 2;
    int mt0 = w, mt1 = w + 4, mt2 = w + 8;

    f32x16 acc[3];
#pragma unroll
    for (int a = 0; a < 3; ++a) acc[a] = (f32x16)0.f;

#pragma unroll
    for (int ks = 0; ks < 16; ++ks) {
        int kofs = ks * 16 + half * 8;
        bf16x8 bfr = *(const bf16x8*)&xb[kofs];
        bf16x8 a0 = *(const bf16x8*)&Wbf[(size_t)(mt0 * 32 + l31) * 256 + kofs];
        acc[0] = __builtin_amdgcn_mfma_f32_32x32x16_bf16(a0, bfr, acc[0], 0, 0, 0);
        bf16x8 a1 = *(const bf16x8*)&Wbf[(size_t)(mt1 * 32 + l31) * 256 + kofs];
        acc[1] = __builtin_amdgcn_mfma_f32_32x32x16_bf16(a1, bfr, acc[1], 0, 0, 0);
        if (nm == 3) {
            bf16x8 a2 = *(const bf16x8*)&Wbf[(size_t)(mt2 * 32 + l31) * 256 + kofs];
            acc[2] = __builtin_amdgcn_mfma_f32_32x32x16_bf16(a2, bfr, acc[2], 0, 0, 0);
        }
    }

    unsigned short* gb = g  + (size_t)b * C8_ * N_;
    unsigned short* hb = hv + (size_t)b * C_  * N_;
#pragma unroll
    for (int im = 0; im < 3; ++im) {
        if (im >= nm) break;
        int mt = (im == 0) ? mt0 : (im == 1) ? mt1 : mt2;
#pragma unroll
        for (int r = 0; r < 16; ++r) {
            int R = mt * 32 + (r & 3) + 8 * (r >> 2) + 4 * half;
            unsigned short v = f2bf(acc[im][r]);
            if (R < 32)       fTg[((size_t)b * N_ + n0 + l31) * 32 + R] = v;
            else if (R < 64)  gb[(size_t)(R - 32) * N_ + n0 + l31] = v;
            else              hb[(size_t)(R - 64) * N_ + n0 + l31] = v;
        }
    }
}

// ---------------- MFMA flash attention, v2 ----------------
// Block: 128 j x 128 c (chalf) x i-range N/SPLITS. 4 waves.
// Scores: wave w -> j-quarter w (duplicated across chalf blocks).
// PV: wave w -> c rows [chalf*128 + w*32, +32), A-frags DIRECT from hv global.
// Score A-frags DIRECT from fTg global. Only pT in LDS, double-buffered,
// ONE barrier per iteration.
__global__ __launch_bounds__(256, 3) void flash_kernel(
    const unsigned short* __restrict__ fTg, const unsigned short* __restrict__ g,
    const unsigned short* __restrict__ hv, unsigned short* __restrict__ o_part,
    float* __restrict__ l_part)
{
    __shared__ unsigned short pT[2][128][72];   // [buf][j][i], row 144B

    int t    = threadIdx.x;
    int w    = t >> 6;
    int lane = t & 63;
    int half = lane >> 5;
    int l31  = lane & 31;

    int j0    = blockIdx.x * TJ;
    int chalf = blockIdx.y;
    int bs    = blockIdx.z;           // b*SPLITS + s
    int b     = bs >> 2;
    int s     = bs & 3;

    const unsigned short* fb = fTg + (size_t)b * N_ * 32;
    const unsigned short* gb = g   + (size_t)b * C8_ * N_;
    const unsigned short* hrow = hv + ((size_t)b * C_ + chalf * 128 + w * 32 + l31) * N_;

    // g B-frags for this wave's j-quarter (k = channel)
    FragAB gf[2];
#pragma unroll
    for (int ks = 0; ks < 2; ++ks)
#pragma unroll
        for (int r = 0; r < 8; ++r) {
            int ch = ks * 16 + half * 8 + r;
            gf[ks].u[r] = gb[(size_t)ch * N_ + j0 + w * 32 + l31];
        }

    f32x16 acc[4];   // jt
#pragma unroll
    for (int a = 0; a < 4; ++a) acc[a] = (f32x16)0.f;
    float lacc = 0.f;

    int i_begin = s * (N_ / SPLITS);

    for (int ii = 0; ii < (N_ / SPLITS) / KI; ++ii) {
        int i0  = i_begin + ii * KI;
        int buf = ii & 1;

        // ---- scores + exp -> pT[buf] (A-frags direct from global) ----
#pragma unroll
        for (int it = 0; it < 2; ++it) {
            f32x16 sacc = (f32x16)0.f;
#pragma unroll
            for (int ks = 0; ks < 2; ++ks) {
                bf16x8 af = *(const bf16x8*)&fb[(size_t)(i0 + it * 32 + l31) * 32
                                                + ks * 16 + half * 8];
                sacc = __builtin_amdgcn_mfma_f32_32x32x16_bf16(af, gf[ks].v, sacc, 0, 0, 0);
            }
            float p[16];
#pragma unroll
            for (int r = 0; r < 16; ++r) {
                p[r] = __expf(sacc[r]);
                lacc += p[r];
            }
            int jr = w * 32 + l31;
#pragma unroll
            for (int a = 0; a < 4; ++a) {
                uint2 v;
                v.x = pack2bf(p[4 * a + 0], p[4 * a + 1]);
                v.y = pack2bf(p[4 * a + 2], p[4 * a + 3]);
                *(uint2*)&pT[buf][jr][it * 32 + 8 * a + 4 * half] = v;
            }
        }
        __syncthreads();   // pT[buf] complete (dbuf makes this the only barrier)

        // ---- PV: A-frags direct from hv global, B-frags from pT[buf] ----
#pragma unroll
        for (int ks4 = 0; ks4 < 4; ++ks4) {
            int kofs = ks4 * 16 + half * 8;
            bf16x8 a = *(const bf16x8*)&hrow[i0 + kofs];
            bf16x8 bfr[4];
#pragma unroll
            for (int jt = 0; jt < 4; ++jt)
                bfr[jt] = *(const bf16x8*)&pT[buf][jt * 32 + l31][kofs];
#pragma unroll
            for (int jt = 0; jt < 4; ++jt)
                acc[jt] = __builtin_amdgcn_mfma_f32_32x32x16_bf16(a, bfr[jt], acc[jt], 0, 0, 0);
        }
    }

    // ---- write bf16 partials ----
    unsigned short* ob = o_part + (size_t)bs * C_ * N_;
#pragma unroll
    for (int jt = 0; jt < 4; ++jt) {
        f32x16 a = acc[jt];
#pragma unroll
        for (int r = 0; r < 16; ++r) {
            int c = chalf * 128 + w * 32 + (r & 3) + 8 * (r >> 2) + 4 * half;
            int j = j0 + jt * 32 + l31;
            ob[(size_t)c * N_ + j] = f2bf(a[r]);
        }
    }
    if (chalf == 0) {
        float lsum = lacc + __shfl_down(lacc, 32);
        if (lane < 32)
            l_part[(size_t)bs * N_ + j0 + w * 32 + lane] = lsum;
    }
}

// ---------------- combine: sum splits, normalize, residual ----------------
__global__ __launch_bounds__(256) void combine_kernel(
    const unsigned short* __restrict__ o_part, const float* __restrict__ l_part,
    const float* __restrict__ x, const float* __restrict__ gamma,
    float* __restrict__ out)
{
    int j = blockIdx.x * 256 + threadIdx.x;
    int b = blockIdx.z;
    float l = 0.f;
#pragma unroll
    for (int s = 0; s < SPLITS; ++s)
        l += l_part[(size_t)(b * SPLITS + s) * N_ + j];
    float inv = 1.f / l;
    float gm = gamma[0];
#pragma unroll
    for (int cc = 0; cc < 4; ++cc) {
        int c = blockIdx.y * 4 + cc;
        float o = 0.f;
#pragma unroll
        for (int s = 0; s < SPLITS; ++s)
            o += bf2f(o_part[((size_t)(b * SPLITS + s) * C_ + c) * N_ + j]);
        size_t idx = ((size_t)b * C_ + c) * N_ + j;
        out[idx] = gm * o * inv + x[idx];
    }
}

extern "C" void kernel_launch(void* const* d_in, const int* in_sizes, int n_in,
                              void* d_out, int out_size, void* d_ws, size_t ws_size,
                              hipStream_t stream) {
    const float* x     = (const float*)d_in[0];
    const float* Wq    = (const float*)d_in[1];
    const float* Wk    = (const float*)d_in[2];
    const float* Wv    = (const float*)d_in[3];
    const float* gamma = (const float*)d_in[4];
    float* out = (float*)d_out;

    char* ws = (char*)d_ws;
    unsigned short* o_part = (unsigned short*)ws;                    // 33.5 MB bf16
    float* l_part = (float*)(o_part + (size_t)SPLITS * B_ * C_ * N_); // 256 KB
    unsigned short* fTg = (unsigned short*)(l_part + (size_t)SPLITS * B_ * N_); // 1 MB
    unsigned short* g   = fTg + (size_t)B_ * C8_ * N_;               // 1 MB
    unsigned short* hv  = g   + (size_t)B_ * C8_ * N_;               // 8 MB
    unsigned short* Wbf = hv  + (size_t)B_ * C_  * N_;               // 160 KB
    unsigned short* xT  = Wbf + (size_t)(C_ + 2 * C8_) * C_;         // 8.4 MB

    prep_w_kernel<<<dim3(80), 256, 0, stream>>>(Wq, Wk, Wv, Wbf);
    prep_x_kernel<<<dim3(N_ / 64, C_ / 64, B_), 256, 0, stream>>>(x, xT);

    proj_mfma_kernel<<<dim3(N_ / 32, B_), 256, 0, stream>>>(Wbf, xT, fTg, g, hv);

    flash_kernel<<<dim3(N_ / TJ, 2, SPLITS * B_), 256, 0, stream>>>(
        fTg, g, hv, o_part, l_part);

    combine_kernel<<<dim3(N_ / 256, C_ / 4, B_), 256, 0, stream>>>(o_part, l_part, x, gamma, out);
}